// Round 14
// baseline (381.308 us; speedup 1.0000x reference)
//
#include <hip/hip_runtime.h>

#define D 64
#define SCAN_CHUNK 1024
#define MAX_CHUNKS 128
#define BSHIFT 9                 // 512 nodes per bucket
#define BNODES (1 << BSHIFT)
#define CHUNK 8192               // edges per partition block

__device__ int g_partials[MAX_CHUNKS];

// ------------------------------------------------ exclusive scan (3 kernels)
__global__ __launch_bounds__(256) void scanA(const int* __restrict__ cnt, int n) {
    __shared__ int red[256];
    int b = blockIdx.x, t = threadIdx.x;
    int base = b * SCAN_CHUNK + t * 4;
    int s = 0;
#pragma unroll
    for (int j = 0; j < 4; ++j) {
        int i = base + j;
        if (i < n) s += cnt[i];
    }
    red[t] = s;
    __syncthreads();
    for (int off = 128; off > 0; off >>= 1) {
        if (t < off) red[t] += red[t + off];
        __syncthreads();
    }
    if (t == 0) g_partials[b] = red[0];
}

__global__ __launch_bounds__(128) void scanB(int nchunks) {
    __shared__ int sh[MAX_CHUNKS];
    int t = threadIdx.x;
    int v = (t < nchunks) ? g_partials[t] : 0;
    sh[t] = v;
    __syncthreads();
    for (int off = 1; off < MAX_CHUNKS; off <<= 1) {
        int a = (t >= off) ? sh[t - off] : 0;
        __syncthreads();
        sh[t] += a;
        __syncthreads();
    }
    if (t < nchunks) g_partials[t] = sh[t] - v;  // exclusive
}

// out-of-place: offs[i] = exclusive_prefix(cnt)[i]  (cnt preserved)
__global__ __launch_bounds__(256) void scanC(const int* __restrict__ cnt,
                                             int* __restrict__ offs, int n) {
    __shared__ int sums[256];
    int b = blockIdx.x, t = threadIdx.x;
    int base = b * SCAN_CHUNK + t * 4;
    int v[4];
    int tot = 0;
#pragma unroll
    for (int j = 0; j < 4; ++j) {
        int i = base + j;
        v[j] = (i < n) ? cnt[i] : 0;
        tot += v[j];
    }
    sums[t] = tot;
    __syncthreads();
    for (int off = 1; off < 256; off <<= 1) {
        int a = (t >= off) ? sums[t - off] : 0;
        __syncthreads();
        sums[t] += a;
        __syncthreads();
    }
    int run = sums[t] - tot + g_partials[b];
#pragma unroll
    for (int j = 0; j < 4; ++j) {
        int i = base + j;
        if (i < n) offs[i] = run;
        run += v[j];
    }
}

// ------------------------------------------------ partAB: per-(chunk,bucket) counts for dst AND src
__global__ __launch_bounds__(256) void partAB(const int* __restrict__ src,
                                              const int* __restrict__ dst,
                                              int* __restrict__ histJ,
                                              int E, int G, int NB, int HL) {
    __shared__ int hD[256], hS[256];
    int g = blockIdx.x;
    hD[threadIdx.x] = 0;
    hS[threadIdx.x] = 0;
    __syncthreads();
    int base = g * CHUNK;
    int lim = min(E - base, CHUNK);
    for (int i = threadIdx.x; i < lim; i += 256) {
        atomicAdd(&hD[dst[base + i] >> BSHIFT], 1);
        atomicAdd(&hS[src[base + i] >> BSHIFT], 1);
    }
    __syncthreads();
    if (threadIdx.x < NB) {
        histJ[threadIdx.x * G + g] = hD[threadIdx.x];
        histJ[HL + threadIdx.x * G + g] = hS[threadIdx.x];
    }
}

// ------------------------------------------------ partCJ: bucket-major reorder for both partitions (SoA)
__global__ __launch_bounds__(256) void partCJ(const int* __restrict__ src,
                                              const int* __restrict__ dst,
                                              const int* __restrict__ histJs,
                                              int* __restrict__ ebufS, int* __restrict__ ebufD,
                                              int* __restrict__ ebufK,
                                              int E, int G, int NB, int HL) {
    __shared__ int curD[256], curK[256];
    int g = blockIdx.x;
    if (threadIdx.x < NB) {
        curD[threadIdx.x] = histJs[threadIdx.x * G + g];
        curK[threadIdx.x] = histJs[HL + threadIdx.x * G + g];
    }
    __syncthreads();
    int base = g * CHUNK;
    int lim = min(E - base, CHUNK);
    for (int i = threadIdx.x; i < lim; i += 256) {
        int d = dst[base + i];
        int s = src[base + i];
        int pD = atomicAdd(&curD[d >> BSHIFT], 1);
        ebufS[pD] = s;
        ebufD[pD] = d;
        int pK = atomicAdd(&curK[s >> BSHIFT], 1) - E;  // src positions offset by E in joint scan
        ebufK[pK] = s;
    }
}

// ------------------------------------------------ partDcount: per-bucket node degrees (LDS), coalesced writes
__global__ __launch_bounds__(256) void partDcount(const int* __restrict__ ebufD,
                                                  const int* __restrict__ ebufK,
                                                  const int* __restrict__ histJs,
                                                  int* __restrict__ cnt_dst, float* __restrict__ rs_src,
                                                  int E, int G, int NB, int HL, int N) {
    __shared__ int cntD[BNODES], cntS[BNODES];
    int b = blockIdx.x;
    int nbase = b << BSHIFT;
    for (int i = threadIdx.x; i < BNODES; i += 256) { cntD[i] = 0; cntS[i] = 0; }
    __syncthreads();
    int dS = histJs[b * G];
    int dE = (b + 1 < NB) ? histJs[(b + 1) * G] : E;
    for (int p = dS + threadIdx.x; p < dE; p += 256)
        atomicAdd(&cntD[ebufD[p] - nbase], 1);
    int kS = histJs[HL + b * G] - E;
    int kE = (b + 1 < NB) ? histJs[HL + (b + 1) * G] - E : E;
    for (int p = kS + threadIdx.x; p < kE; p += 256)
        atomicAdd(&cntS[ebufK[p] - nbase], 1);
    __syncthreads();
    for (int i = threadIdx.x; i < BNODES; i += 256) {
        int node = nbase + i;
        if (node < N) {
            cnt_dst[node] = cntD[i];
            rs_src[node] = rsqrtf((float)max(cntS[i], 1));
        }
    }
}

// ------------------------------------------------ partD2: per-bucket local scatter (LDS cursors)
// Writes fused int2 {src, w=rs_src[src]} so gather needs ONE load per edge.
__global__ __launch_bounds__(256) void partD2(const int* __restrict__ ebufS,
                                              const int* __restrict__ ebufD,
                                              const int* __restrict__ histJs,
                                              const int* __restrict__ offs,
                                              const float* __restrict__ rs_src,
                                              int2* __restrict__ sortedEW,
                                              int E, int G, int NB, int N) {
    __shared__ int cur[BNODES];
    int b = blockIdx.x;
    int nbase = b << BSHIFT;
    for (int i = threadIdx.x; i < BNODES; i += 256) {
        int node = nbase + i;
        cur[i] = (node < N) ? offs[node] : 0;
    }
    __syncthreads();
    int dS = histJs[b * G];
    int dE = (b + 1 < NB) ? histJs[(b + 1) * G] : E;
    for (int p = dS + threadIdx.x; p < dE; p += 256) {
        int d = ebufD[p];
        int s = ebufS[p];
        float w = rs_src[s];              // 400KB table, L2-hot
        int pos = atomicAdd(&cur[d - nbase], 1);
        sortedEW[pos] = make_int2(s, __float_as_int(w));
    }
}

// ------------------------------------------------ gather: S[i] = rs_dst[i] * sum w_e * X[src_e]
// 2 nodes per wave: half-wave (32 lanes) covers a 64-float row as float2.
// One ew-load instr fetches 2 edges (one per half); one row-load instr fetches
// 2 rows. Fast loop to cmin (no clamping), masked slow loop to cmax.
// R10 rationale: gather was ISSUE-bound (~8 wave-instrs/edge); this is ~3.
__global__ __launch_bounds__(256) void gather_kernel(
    const int* __restrict__ offs, const int* __restrict__ cnt_dst,
    const int2* __restrict__ sortedEW,
    const float* __restrict__ X, float* __restrict__ S, int n) {
    int t = threadIdx.x;
    int lane = t & 63;
    int half = lane >> 5;
    int col2 = (lane & 31) * 2;
    int wid = blockIdx.x * (blockDim.x >> 6) + (t >> 6);
    int node = wid * 2 + half;
    int nc = min(node, n - 1);
    int start = offs[nc];
    int cnt = (node < n) ? cnt_dst[nc] : 0;
    int end = start + cnt;
    int cntO = __shfl_xor(cnt, 32, 64);
    int cmin = min(cnt, cntO);
    int cmax = max(cnt, cntO);

    float2 acc = make_float2(0.f, 0.f);
    const float* Xc = X + col2;
    int j = 0;
    // ---- fast path: both halves in-range, no clamping/masking
    for (; j + 8 <= cmin; j += 8) {
        int2 ew[8];
#pragma unroll
        for (int u = 0; u < 8; ++u) ew[u] = sortedEW[start + j + u];
        float2 r[8];
#pragma unroll
        for (int u = 0; u < 8; ++u) r[u] = *(const float2*)(Xc + (size_t)ew[u].x * D);
#pragma unroll
        for (int u = 0; u < 8; ++u) {
            float w = __int_as_float(ew[u].y);
            acc.x = fmaf(w, r[u].x, acc.x);
            acc.y = fmaf(w, r[u].y, acc.y);
        }
    }
    // ---- slow path: clamped addresses + masked weights, 8 at a time
    for (; j < cmax; j += 8) {
        int2 ew[8];
#pragma unroll
        for (int u = 0; u < 8; ++u) {
            int qc = max(min(start + j + u, end - 1), 0);
            ew[u] = sortedEW[qc];
        }
        float2 r[8];
#pragma unroll
        for (int u = 0; u < 8; ++u) r[u] = *(const float2*)(Xc + (size_t)ew[u].x * D);
#pragma unroll
        for (int u = 0; u < 8; ++u) {
            float w = (j + u < cnt) ? __int_as_float(ew[u].y) : 0.0f;
            acc.x = fmaf(w, r[u].x, acc.x);
            acc.y = fmaf(w, r[u].y, acc.y);
        }
    }
    if (node < n) {
        float rd = rsqrtf((float)max(cnt, 1));
        *(float2*)(S + (size_t)node * D + col2) = make_float2(acc.x * rd, acc.y * rd);
    }
}

// ------------------------------------------------ combine: Out = (X+S)@W1 + (X*S)@W2
// Block = 64 rows; stage 64x64 x/s tile once ([64][65] pad), ONE barrier; wave
// wv computes cols [16wv,16wv+16) for all 64 rows; W uniform -> s_load.
__global__ __launch_bounds__(256, 4) void combine_kernel(
    const float* X, const float* S,
    const float* __restrict__ W1, const float* __restrict__ W2,
    float* Out, int n, int relu_flag) {
    __shared__ float xs[64][65];
    __shared__ float ss[64][65];
    int t = threadIdx.x;
    int rowBase = blockIdx.x * 64;
    int lane = t & 63;
    int wv = __builtin_amdgcn_readfirstlane(t >> 6);
    int q = t & 15;
    int sr = t >> 4;

#pragma unroll
    for (int p = 0; p < 4; ++p) {
        int r = p * 16 + sr;
        int g = min(rowBase + r, n - 1);
        float4 xv = *(const float4*)(X + (size_t)g * D + q * 4);
        float4 sv = *(const float4*)(S + (size_t)g * D + q * 4);
        int c = q * 4;
        xs[r][c + 0] = xv.x; xs[r][c + 1] = xv.y;
        xs[r][c + 2] = xv.z; xs[r][c + 3] = xv.w;
        ss[r][c + 0] = sv.x; ss[r][c + 1] = sv.y;
        ss[r][c + 2] = sv.z; ss[r][c + 3] = sv.w;
    }
    __syncthreads();

    float4 A0 = make_float4(0.f, 0.f, 0.f, 0.f);
    float4 A1 = A0, A2 = A0, A3 = A0;
    const float* W1c = W1 + wv * 16;
    const float* W2c = W2 + wv * 16;
#pragma unroll 2
    for (int j = 0; j < 64; ++j) {
        float xk = xs[lane][j];
        float sk = ss[lane][j];
        float u = xk + sk;
        float v = xk * sk;
        float4 w10 = *(const float4*)(W1c + j * D + 0);
        float4 w11 = *(const float4*)(W1c + j * D + 4);
        float4 w12 = *(const float4*)(W1c + j * D + 8);
        float4 w13 = *(const float4*)(W1c + j * D + 12);
        float4 w20 = *(const float4*)(W2c + j * D + 0);
        float4 w21 = *(const float4*)(W2c + j * D + 4);
        float4 w22 = *(const float4*)(W2c + j * D + 8);
        float4 w23 = *(const float4*)(W2c + j * D + 12);
        A0.x = fmaf(u, w10.x, fmaf(v, w20.x, A0.x));
        A0.y = fmaf(u, w10.y, fmaf(v, w20.y, A0.y));
        A0.z = fmaf(u, w10.z, fmaf(v, w20.z, A0.z));
        A0.w = fmaf(u, w10.w, fmaf(v, w20.w, A0.w));
        A1.x = fmaf(u, w11.x, fmaf(v, w21.x, A1.x));
        A1.y = fmaf(u, w11.y, fmaf(v, w21.y, A1.y));
        A1.z = fmaf(u, w11.z, fmaf(v, w21.z, A1.z));
        A1.w = fmaf(u, w11.w, fmaf(v, w21.w, A1.w));
        A2.x = fmaf(u, w12.x, fmaf(v, w22.x, A2.x));
        A2.y = fmaf(u, w12.y, fmaf(v, w22.y, A2.y));
        A2.z = fmaf(u, w12.z, fmaf(v, w22.z, A2.z));
        A2.w = fmaf(u, w12.w, fmaf(v, w22.w, A2.w));
        A3.x = fmaf(u, w13.x, fmaf(v, w23.x, A3.x));
        A3.y = fmaf(u, w13.y, fmaf(v, w23.y, A3.y));
        A3.z = fmaf(u, w13.z, fmaf(v, w23.z, A3.z));
        A3.w = fmaf(u, w13.w, fmaf(v, w23.w, A3.w));
    }

    int row0 = rowBase + lane;
    if (row0 < n) {
        if (relu_flag) {
            A0.x = fmaxf(A0.x, 0.f); A0.y = fmaxf(A0.y, 0.f);
            A0.z = fmaxf(A0.z, 0.f); A0.w = fmaxf(A0.w, 0.f);
            A1.x = fmaxf(A1.x, 0.f); A1.y = fmaxf(A1.y, 0.f);
            A1.z = fmaxf(A1.z, 0.f); A1.w = fmaxf(A1.w, 0.f);
            A2.x = fmaxf(A2.x, 0.f); A2.y = fmaxf(A2.y, 0.f);
            A2.z = fmaxf(A2.z, 0.f); A2.w = fmaxf(A2.w, 0.f);
            A3.x = fmaxf(A3.x, 0.f); A3.y = fmaxf(A3.y, 0.f);
            A3.z = fmaxf(A3.z, 0.f); A3.w = fmaxf(A3.w, 0.f);
        }
        float4* o4 = (float4*)(Out + (size_t)row0 * D + wv * 16);
        o4[0] = A0; o4[1] = A1; o4[2] = A2; o4[3] = A3;
    }
}

extern "C" void kernel_launch(void* const* d_in, const int* in_sizes, int n_in,
                              void* d_out, int out_size, void* d_ws, size_t ws_size,
                              hipStream_t stream) {
    const float* x    = (const float*)d_in[0];
    const int*   src  = (const int*)d_in[1];
    const int*   dst  = (const int*)d_in[2];
    const float* W1_1 = (const float*)d_in[3];
    const float* W2_1 = (const float*)d_in[4];
    const float* W1_2 = (const float*)d_in[5];
    const float* W2_2 = (const float*)d_in[6];
    float* out = (float*)d_out;

    const int N = in_sizes[0] / D;
    const int E = in_sizes[1];

    const int NB = (N + BNODES - 1) >> BSHIFT;     // node buckets (196 for N=100000)
    const int G  = (E + CHUNK - 1) / CHUNK;        // partition chunks (196)
    const int HL = NB * G;

    // ws layout (4B units):
    // cnt_dst[N] | offs[N] | rs_src[N] | sortedEW[2E] | histJ[2HL] | histJs[2HL] | S[N*D]
    // ebufS/ebufD/ebufK alias S (19.2MB < 25.6MB; all dead before gather writes S).
    int*   cnt_dst   = (int*)d_ws;
    int*   offs      = cnt_dst + N;
    float* rs_src    = (float*)(cnt_dst + 2 * (size_t)N);
    int2*  sortedEW  = (int2*)(cnt_dst + 3 * (size_t)N);
    int*   histJ     = (int*)(sortedEW + E);
    int*   histJs    = histJ + 2 * (size_t)HL;
    float* S         = (float*)(histJs + 2 * (size_t)HL);
    int*   ebufS     = (int*)S;
    int*   ebufD     = ebufS + E;
    int*   ebufK     = ebufD + E;

    const int tb = 256;
    const int g_blocks = (N / 2 + 3) / 4 + 1;      // 2 nodes/wave, 4 waves/block
    const int c_blocks = (N + 63) / 64;
    const int nchunksN = (N + SCAN_CHUNK - 1) / SCAN_CHUNK;
    const int nchunksJ = (2 * HL + SCAN_CHUNK - 1) / SCAN_CHUNK;

    // ---- joint bucket histograms (dst + src) and joint scan
    partAB<<<G, tb, 0, stream>>>(src, dst, histJ, E, G, NB, HL);
    scanA<<<nchunksJ, tb, 0, stream>>>(histJ, 2 * HL);
    scanB<<<1, 128, 0, stream>>>(nchunksJ);
    scanC<<<nchunksJ, tb, 0, stream>>>(histJ, histJs, 2 * HL);

    // ---- bucket-major reorder for both partitions
    partCJ<<<G, tb, 0, stream>>>(src, dst, histJs, ebufS, ebufD, ebufK, E, G, NB, HL);

    // ---- per-node degrees (coalesced, no global atomics) + rs_src
    partDcount<<<NB, tb, 0, stream>>>(ebufD, ebufK, histJs, cnt_dst, rs_src, E, G, NB, HL, N);

    // ---- offs = exclusive scan of cnt_dst
    scanA<<<nchunksN, tb, 0, stream>>>(cnt_dst, N);
    scanB<<<1, 128, 0, stream>>>(nchunksN);
    scanC<<<nchunksN, tb, 0, stream>>>(cnt_dst, offs, N);

    // ---- CSR scatter with fused {src, w} records
    partD2<<<NB, tb, 0, stream>>>(ebufS, ebufD, histJs, offs, rs_src, sortedEW, E, G, NB, N);

    // ---- layer 1: h = relu((x+S)@W1_1 + (x*S)@W2_1), h lives in d_out
    gather_kernel<<<g_blocks, tb, 0, stream>>>(offs, cnt_dst, sortedEW, x, S, N);
    combine_kernel<<<c_blocks, tb, 0, stream>>>(x, S, W1_1, W2_1, out, N, 1);

    // ---- layer 2: out = (h+S)@W1_2 + (h*S)@W2_2
    gather_kernel<<<g_blocks, tb, 0, stream>>>(offs, cnt_dst, sortedEW, out, S, N);
    combine_kernel<<<c_blocks, tb, 0, stream>>>(out, S, W1_2, W2_2, out, N, 0);
}